// Round 8
// baseline (654.129 us; speedup 1.0000x reference)
//
#include <hip/hip_runtime.h>

// Problem dims (fixed by the reference)
#define BB 4        // batch
#define CC 4096     // channels
#define TT 2048     // timesteps
#define BS 16       // block size
#define KK 100      // IRF taps
#define NNZ 1024    // nonzero blocks
#define NB (CC / BS)
#define TC 512              // timestep chunk per WG (4 waves x 128 steps)
#define NCH (TT / TC)       // 4 chunks
#define MAXM 64             // max blocks per output row
#define WPAD 128            // history staged before t0 (>= KK, f4-aligned)
#define WIN (WPAD + TC)     // 640 staged floats per row
#define SSTR 644            // LDS row stride (mod 32 == 4, 16B-aligned)

// acc + DPP-permuted src (GCNDPPCombine fuses mov_dpp+add -> v_add_f32_dpp)
template <int CTRL>
__device__ __forceinline__ float add_dpp(float acc, float src) {
    int m = __builtin_amdgcn_update_dpp(0, __builtin_bit_cast(int, src),
                                        CTRL, 0xF, 0xF, true);
    return acc + __builtin_bit_cast(float, m);
}
// keep + (send from lane^4) via ds_swizzle  (R4-proven)
__device__ __forceinline__ float add_xor4(float keep, float send) {
    int m = __builtin_amdgcn_ds_swizzle(__builtin_bit_cast(int, send), 0x101F);
    return keep + __builtin_bit_cast(float, m);
}

// ---- R4-proven select-butterfly over j (lane bits 0-3).
// Stages: xor1(sel j0), xor2(sel j1), xor8(sel j3), xor4(sel j2, ds_swizzle).
// Valid: each stage's mask is disjoint from all earlier selection bits.
// Lane j ends holding the full 16-lane sum for t-phase j (identity map).
__device__ __forceinline__ float butterfly16(const float (&v)[16], int j) {
    const bool q0 = (j & 1) != 0;
    const bool q1 = (j & 2) != 0;
    const bool q2 = (j & 4) != 0;
    const bool q3 = (j & 8) != 0;
    float u[8];
#pragma unroll
    for (int p = 0; p < 8; ++p) {
        float keep = q0 ? v[2 * p + 1] : v[2 * p];
        float send = q0 ? v[2 * p]     : v[2 * p + 1];
        u[p] = add_dpp<0xB1>(keep, send);            // quad_perm xor1
    }
    float w[4];
#pragma unroll
    for (int p = 0; p < 4; ++p) {
        float keep = q1 ? u[2 * p + 1] : u[2 * p];
        float send = q1 ? u[2 * p]     : u[2 * p + 1];
        w[p] = add_dpp<0x4E>(keep, send);            // quad_perm xor2
    }
    float z[2];
#pragma unroll
    for (int p = 0; p < 2; ++p) {
        float keep = q3 ? w[p + 2] : w[p];
        float send = q3 ? w[p]     : w[p + 2];
        z[p] = add_dpp<0x128>(keep, send);           // row_ror:8 == xor8
    }
    float keep = q2 ? z[1] : z[0];
    float send = q2 ? z[0] : z[1];
    return add_xor4(keep, send);                     // xor4 via ds_swizzle
}

// ------------- prep: per-row block lists, deterministic (no atomics) -------
__global__ void lti_build_lists(const int* __restrict__ rows,
                                int* __restrict__ cnt,
                                int* __restrict__ list) {
    int r = threadIdx.x;            // one thread per output row, single WG
    if (r >= NB) return;
    int m = 0;
    for (int n = 0; n < NNZ; ++n)
        if (rows[n] == r && m < MAXM) list[r * MAXM + m++] = n;
    cnt[r] = m;
}

// ------------- router: one WG per (row-block r, batch b, 512-chunk) --------
// Wave wv owns t-subwindow [t0 + wv*128, t0 + (wv+1)*128); each lane runs
// 4 filters (output rows i = ii*4 + iw) sharing one staged x-tile read.
__global__ __launch_bounds__(256) void lti_router(
    const float* __restrict__ x,       // runoff [B, C, T]
    const float* __restrict__ params,  // [NNZ, BS, BS]
    const int* __restrict__ cols,      // [NNZ]
    const int* __restrict__ cnt,       // [NB]
    const int* __restrict__ list,      // [NB, MAXM]
    float* __restrict__ out)           // [B, C, T]
{
    const int r   = blockIdx.x;
    const int b   = blockIdx.y;
    const int t0  = blockIdx.z * TC;
    const int tid = threadIdx.x;
    const int j   = tid & 15;          // input row within block (lane bits 0-3)
    const int iw  = (tid >> 4) & 3;    // i sub-index (lane bits 4-5)
    const int wv  = tid >> 6;          // wave id 0..3 -> t-subwindow

    __shared__ __align__(16) float xs[16 * SSTR];

    // acc[ii][p]: y at t = t0 + wv*128 + p*16 + j, output row ii*4+iw
    float acc[4][8];
#pragma unroll
    for (int ii = 0; ii < 4; ++ii)
#pragma unroll
        for (int p = 0; p < 8; ++p) acc[ii][p] = 0.0f;

    const int m = cnt[r];
    for (int bi = 0; bi < m; ++bi) {
        const int n = list[r * MAXM + bi];
        const int c = cols[n];
        const float* __restrict__ xb =
            x + ((size_t)b * CC + (size_t)c * BS) * TT;

        // ---- stage x[b, c*16 + row, t0-128 .. t0+512) into LDS (f4) ----
#pragma unroll
        for (int k = 0; k < 10; ++k) {
            const int f    = tid + k * 256;      // 0 .. 2559
            const int row  = f / 160;            // 0 .. 15
            const int col4 = f - row * 160;      // 0 .. 159
            const int t    = t0 - WPAD + col4 * 4;
            float4 v;
            if (t >= 0) v = *(const float4*)(xb + (size_t)row * TT + t);
            else        v = make_float4(0.f, 0.f, 0.f, 0.f);
            *(float4*)&xs[row * SSTR + col4 * 4] = v;
        }
        __syncthreads();

        // ---- per-entry IRF params: 4 filters per lane ----
        // filter (i = ii*4 + iw, j): params[n*256 + i*16 + j]
        //   = params[n*256 + ii*64 + (iw*16 + j)] = pp[ii*64]
        const float* __restrict__ pp = params + n * (BS * BS) + (tid & 63);
        float aa[4], oo[4];
#pragma unroll
        for (int ii = 0; ii < 4; ++ii) {
            const float pv  = pp[ii * 64];
            const float tau = 1.0f + 19.0f * pv;
            aa[ii] = __expf(-1.0f / tau);
            oo[ii] = 1.0f - aa[ii];
        }

        // ---- bootstrap: 4 interleaved Horner chains from LDS ----
        // taps t in [W-100, W-1], W = t0 + wv*128; window idx = wv*128+28..127
        // (chunk 0 / wave 0 reads the zero-filled pad -> s = 0, exact)
        float s[4] = {0.f, 0.f, 0.f, 0.f};
        {
            const float* __restrict__ hb = &xs[j * SSTR + wv * 128 + 28];
#pragma unroll 5
            for (int q = 0; q < 25; ++q) {
                float4 h = *(const float4*)(hb + 4 * q);
#pragma unroll
                for (int ii = 0; ii < 4; ++ii) {
                    s[ii] = fmaf(aa[ii], s[ii], h.x);
                    s[ii] = fmaf(aa[ii], s[ii], h.y);
                    s[ii] = fmaf(aa[ii], s[ii], h.z);
                    s[ii] = fmaf(aa[ii], s[ii], h.w);
                }
            }
        }

        // ---- main: 8 tiles of 16 steps; one x16 read feeds 4 filters ----
        const float* __restrict__ xt = &xs[j * SSTR + WPAD + wv * 128];
#pragma unroll
        for (int tb = 0; tb < 8; ++tb) {
            float4 X0 = *(const float4*)(xt + tb * 16 + 0);
            float4 X1 = *(const float4*)(xt + tb * 16 + 4);
            float4 X2 = *(const float4*)(xt + tb * 16 + 8);
            float4 X3 = *(const float4*)(xt + tb * 16 + 12);
            float xv[16];
            xv[0]=X0.x;  xv[1]=X0.y;  xv[2]=X0.z;  xv[3]=X0.w;
            xv[4]=X1.x;  xv[5]=X1.y;  xv[6]=X1.z;  xv[7]=X1.w;
            xv[8]=X2.x;  xv[9]=X2.y;  xv[10]=X2.z; xv[11]=X2.w;
            xv[12]=X3.x; xv[13]=X3.y; xv[14]=X3.z; xv[15]=X3.w;

#pragma unroll
            for (int ii = 0; ii < 4; ++ii) {
                const float av  = aa[ii];
                const float oma = oo[ii];
                float v[16];
#pragma unroll
                for (int t = 0; t < 16; ++t) {
                    s[ii] = fmaf(av, s[ii], xv[t]);
                    v[t] = oma * s[ii];
                }
                acc[ii][tb] += butterfly16(v, j);
            }
        }
        __syncthreads();   // before next block overwrites xs
    }

    // ---- epilogue: out = runoff + y; lane j holds phase j (identity) ----
#pragma unroll
    for (int ii = 0; ii < 4; ++ii) {
        const int i = ii * 4 + iw;
        const size_t obase =
            ((size_t)b * CC + (size_t)r * BS + i) * TT + t0 + wv * 128;
#pragma unroll
        for (int p = 0; p < 8; ++p) {
            const size_t idx = obase + p * 16 + j;
            out[idx] = x[idx] + acc[ii][p];
        }
    }
}

extern "C" void kernel_launch(void* const* d_in, const int* in_sizes, int n_in,
                              void* d_out, int out_size, void* d_ws, size_t ws_size,
                              hipStream_t stream) {
    const float* runoff = (const float*)d_in[0];
    const float* params = (const float*)d_in[1];
    const int* rows = (const int*)d_in[2];
    const int* cols = (const int*)d_in[3];
    float* out = (float*)d_out;

    // ws layout: cnt [NB] ints @ 0, list [NB*MAXM] ints @ 1024 bytes
    int* cnt  = (int*)d_ws;
    int* list = (int*)((char*)d_ws + 1024);

    lti_build_lists<<<1, 256, 0, stream>>>(rows, cnt, list);

    dim3 grid(NB, BB, NCH);
    lti_router<<<grid, 256, 0, stream>>>(runoff, params, cols, cnt, list, out);
}